// Round 8
// baseline (1501.588 us; speedup 1.0000x reference)
//
#include <hip/hip_runtime.h>

#define T_STEPS 1024
#define BATCH   64
#define NIN     32
#define NH      256
#define NOUT    16

typedef __attribute__((ext_vector_type(8))) _Float16 half8;
typedef __attribute__((ext_vector_type(4))) _Float16 half4;
typedef __attribute__((ext_vector_type(4))) float    f32x4;

__device__ __forceinline__ float fast_tanh(float x) {
  // tanh(x) = 1 - 2/(exp2(2*log2e*x)+1); exp2->inf/0 gives correct +-1 tails
  float e = __builtin_amdgcn_exp2f(x * 2.8853900817779268f);
  return 1.0f - 2.0f * __builtin_amdgcn_rcpf(e + 1.0f);
}

// LDS layout (round-2, conflict-verified): rlds[buf][m][...] ushort, row
// stride 320 (40 blocks of 8); element n at blk=(n>>3)^(m&7), j=n&7;
// u (k=256..287) at blk=(32+q)^(m&7).
#define ROW 320
#define BUFSZ (16 * 320)

// Round-12: intra-step nt-split pipeline on the round-11 core.
//  Round-7 counters: VALUBusy 0.53 + MfmaUtil 0.34 ~ additive => the
//  barrier-locked schedule serializes [K-loop MFMA] then [VALU/trans tail].
//  nt=0 and nt=1 accumulators are independent given the same 8 staged
//  B-fragments, so: stage bf[1..8] -> regs, run nt0's 9 MFMAs, then nt0's
//  FULL tail (x-update, tanh, cvt, ds_write, x-store) while nt1's 9 MFMAs
//  occupy the matrix pipe — the exposed tail roughly halves.
//  Micros: q_t folded into accB init (x = fma(0.9,x,A+B), 2 VALU/elem);
//  x-stores split per-nt into the overlap gaps.
//  Kept (round-7 verified): own-frag bypass w/ rotated kt order, running
//  pointers, cvt_pkrtz, lgkmcnt(0)+s_barrier protocol, z in phase-2.

__global__ __launch_bounds__(512, 2)
void RecurrentNetwork_19628000543215_kernel(
    const float* __restrict__ inputs,  // [T][B][NIN]
    const float* __restrict__ noise,   // [T][B][NH]
    const float* __restrict__ x0,      // [B][NH]
    const float* __restrict__ Win,     // [NIN][NH]
    const float* __restrict__ Wrec,    // [NH][NH]
    const float* __restrict__ brec,    // [NH]
    float* __restrict__ outx)          // states [T][B][NH]
{
  __shared__ alignas(16) unsigned short rlds[2 * BUFSZ];

  const int g   = blockIdx.x;       // batch group: batches [16g, 16g+16)
  const int tid = threadIdx.x;
  const int w   = tid >> 6;         // wave 0..7: owns n-columns [32w, 32w+32)
  const int l   = tid & 63;
  const int m   = l & 15;           // batch-in-group (B col / C col)
  const int q   = l >> 4;           // quad
  const int b   = 16 * g + m;       // global batch
  const int mx  = m & 7;            // LDS swizzle key

  // ---- weights in ROTATED kt order: slot i holds kt=(w+i)%9; i=0 is the
  // wave's own fragment. A-frag (16x16x32): row=lane&15, k=32*kt+8*q+j.
  half8 wr[2][9];                   // kt 0..7 = 0.1*Wrec^T, kt 8 = 0.1*Win^T
  int   ldso[9];                    // LDS ushort-offset of fragment slot i
  #pragma unroll
  for (int i = 0; i < 9; ++i) {
    int kt = w + i; if (kt >= 9) kt -= 9;
    ldso[i] = m * ROW + ((((4 * kt + q) ^ mx)) << 3);
    #pragma unroll
    for (int nt = 0; nt < 2; ++nt) {
      const int n = 32 * w + 16 * nt + m;
      #pragma unroll
      for (int j = 0; j < 8; ++j) {
        const int k = 32 * kt + 8 * q + j;
        const float v = (kt < 8) ? Wrec[(size_t)k * NH + n]
                                 : Win[(size_t)(k - 256) * NH + n];
        wr[nt][i][j] = (_Float16)(0.1f * v);
      }
    }
  }

  f32x4 brecs[2], x[2];
  #pragma unroll
  for (int nt = 0; nt < 2; ++nt) {
    const int n0 = 32 * w + 16 * nt + 4 * q;
    brecs[nt] = 0.1f * (*(const f32x4*)(brec + n0));
    x[nt]     = *(const f32x4*)(x0 + (size_t)b * NH + n0);
  }

  // ---- preloop: r_{-1}=tanh(x0), u_0 -> buf0; q_0 -> regs ----
  #pragma unroll
  for (int nt = 0; nt < 2; ++nt) {
    const int n0 = 32 * w + 16 * nt + 4 * q;
    half4 r;
    r.x = (_Float16)fast_tanh(x[nt].x);
    r.y = (_Float16)fast_tanh(x[nt].y);
    r.z = (_Float16)fast_tanh(x[nt].z);
    r.w = (_Float16)fast_tanh(x[nt].w);
    const int blk = (n0 >> 3) ^ mx;
    *(half4*)&rlds[m * ROW + blk * 8 + (n0 & 7)] = r;
  }
  if (w == 1) {
    const float* up = inputs + (size_t)b * NIN + 8 * q;   // t = 0
    const f32x4 ua = *(const f32x4*)up;
    const f32x4 ub = *(const f32x4*)(up + 4);
    half8 uu;
    uu[0]=(_Float16)ua.x; uu[1]=(_Float16)ua.y; uu[2]=(_Float16)ua.z; uu[3]=(_Float16)ua.w;
    uu[4]=(_Float16)ub.x; uu[5]=(_Float16)ub.y; uu[6]=(_Float16)ub.z; uu[7]=(_Float16)ub.w;
    const int blk = (32 + q) ^ mx;
    *(half8*)&rlds[m * ROW + blk * 8] = uu;
  }
  f32x4 qv[2];
  qv[0] = *(const f32x4*)(noise + (size_t)b * NH + 32 * w + 4 * q);   // q_0
  qv[1] = *(const f32x4*)(noise + (size_t)b * NH + 32 * w + 16 + 4 * q);
  __syncthreads();

  half8 bfw = *(const half8*)&rlds[ldso[0]];   // own fragment, buf0

  // running prefetch/store pointers (avoid per-step 64-bit mul + clamp)
  const float* np = noise  + (size_t)BATCH * NH  + (size_t)b * NH  + 32 * w + 4 * q;
  const float* ip = inputs + (size_t)BATCH * NIN + (size_t)b * NIN + 8 * q;
  float*       xp = outx   + (size_t)b * NH + 32 * w + 4 * q;

  // ---- time loop ----
  #pragma unroll 1
  for (int t = 0; t < T_STEPS; ++t) {
    const int rb = (t & 1) * BUFSZ;
    const int wb = BUFSZ - rb;

    f32x4 ua, ub;                   // wave 1: u_{t+1} load issued early
    if (w == 1) {
      ua = *(const f32x4*)ip;
      ub = *(const f32x4*)(ip + 4);
    }
    // q_{t+1} prefetch (row min(t+1,1023) via gated pointer increment)
    const f32x4 qn0 = *(const f32x4*)np;
    const f32x4 qn1 = *(const f32x4*)(np + 16);

    // stage the 8 foreign B-fragments into registers (shared by both nt)
    half8 bf1 = *(const half8*)&rlds[rb + ldso[1]];
    half8 bf2 = *(const half8*)&rlds[rb + ldso[2]];
    half8 bf3 = *(const half8*)&rlds[rb + ldso[3]];
    half8 bf4 = *(const half8*)&rlds[rb + ldso[4]];
    half8 bf5 = *(const half8*)&rlds[rb + ldso[5]];
    half8 bf6 = *(const half8*)&rlds[rb + ldso[6]];
    half8 bf7 = *(const half8*)&rlds[rb + ldso[7]];
    half8 bf8 = *(const half8*)&rlds[rb + ldso[8]];

    // ---- nt=0: acc chains (q_t folded into B-chain init) ----
    f32x4 a0 = brecs[0], b0 = qv[0];
    a0 = __builtin_amdgcn_mfma_f32_16x16x32_f16(wr[0][0], bfw, a0, 0, 0, 0);
    b0 = __builtin_amdgcn_mfma_f32_16x16x32_f16(wr[0][1], bf1, b0, 0, 0, 0);
    a0 = __builtin_amdgcn_mfma_f32_16x16x32_f16(wr[0][2], bf2, a0, 0, 0, 0);
    b0 = __builtin_amdgcn_mfma_f32_16x16x32_f16(wr[0][3], bf3, b0, 0, 0, 0);
    a0 = __builtin_amdgcn_mfma_f32_16x16x32_f16(wr[0][4], bf4, a0, 0, 0, 0);
    b0 = __builtin_amdgcn_mfma_f32_16x16x32_f16(wr[0][5], bf5, b0, 0, 0, 0);
    a0 = __builtin_amdgcn_mfma_f32_16x16x32_f16(wr[0][6], bf6, a0, 0, 0, 0);
    b0 = __builtin_amdgcn_mfma_f32_16x16x32_f16(wr[0][7], bf7, b0, 0, 0, 0);
    a0 = __builtin_amdgcn_mfma_f32_16x16x32_f16(wr[0][8], bf8, a0, 0, 0, 0);

    // nt=0 tail: x-update, tanh, cvt, ds_write, x-store — overlaps nt=1
    // MFMAs below (independent given staged bf registers)
    x[0] = 0.9f * x[0] + (a0 + b0);
    {
      const int n0 = 32 * w + 4 * q;
      half4 r;
      auto plo = __builtin_amdgcn_cvt_pkrtz(fast_tanh(x[0].x), fast_tanh(x[0].y));
      auto phi = __builtin_amdgcn_cvt_pkrtz(fast_tanh(x[0].z), fast_tanh(x[0].w));
      r.x = plo.x; r.y = plo.y; r.z = phi.x; r.w = phi.y;
      const int blk = (n0 >> 3) ^ mx;
      *(half4*)&rlds[wb + m * ROW + blk * 8 + (n0 & 7)] = r;
    }
    *(f32x4*)(xp) = x[0];

    // ---- nt=1: acc chains ----
    f32x4 a1 = brecs[1], b1 = qv[1];
    a1 = __builtin_amdgcn_mfma_f32_16x16x32_f16(wr[1][0], bfw, a1, 0, 0, 0);
    b1 = __builtin_amdgcn_mfma_f32_16x16x32_f16(wr[1][1], bf1, b1, 0, 0, 0);
    a1 = __builtin_amdgcn_mfma_f32_16x16x32_f16(wr[1][2], bf2, a1, 0, 0, 0);
    b1 = __builtin_amdgcn_mfma_f32_16x16x32_f16(wr[1][3], bf3, b1, 0, 0, 0);
    a1 = __builtin_amdgcn_mfma_f32_16x16x32_f16(wr[1][4], bf4, a1, 0, 0, 0);
    b1 = __builtin_amdgcn_mfma_f32_16x16x32_f16(wr[1][5], bf5, b1, 0, 0, 0);
    a1 = __builtin_amdgcn_mfma_f32_16x16x32_f16(wr[1][6], bf6, a1, 0, 0, 0);
    b1 = __builtin_amdgcn_mfma_f32_16x16x32_f16(wr[1][7], bf7, b1, 0, 0, 0);
    a1 = __builtin_amdgcn_mfma_f32_16x16x32_f16(wr[1][8], bf8, a1, 0, 0, 0);

    x[1] = 0.9f * x[1] + (a1 + b1);
    {
      const int n0 = 32 * w + 16 + 4 * q;
      half4 r;
      auto plo = __builtin_amdgcn_cvt_pkrtz(fast_tanh(x[1].x), fast_tanh(x[1].y));
      auto phi = __builtin_amdgcn_cvt_pkrtz(fast_tanh(x[1].z), fast_tanh(x[1].w));
      r.x = plo.x; r.y = plo.y; r.z = phi.x; r.w = phi.y;
      const int blk = (n0 >> 3) ^ mx;
      *(half4*)&rlds[wb + m * ROW + blk * 8 + (n0 & 7)] = r;
    }
    *(f32x4*)(xp + 16) = x[1];

    if (w == 1) {                   // stage u_{t+1}
      half8 uu;
      uu[0]=(_Float16)ua.x; uu[1]=(_Float16)ua.y; uu[2]=(_Float16)ua.z; uu[3]=(_Float16)ua.w;
      uu[4]=(_Float16)ub.x; uu[5]=(_Float16)ub.y; uu[6]=(_Float16)ub.z; uu[7]=(_Float16)ub.w;
      const int blk = (32 + q) ^ mx;
      *(half8*)&rlds[wb + m * ROW + blk * 8] = uu;
    }

    // own-fragment self-read for step t+1 (wave-local bytes of wb; LDS is
    // in-order within a wave => sees our writes above; drained by the
    // lgkmcnt(0) below, so next step starts with bfw already in regs)
    asm volatile("" ::: "memory");  // keep this read below the writes
    bfw = *(const half8*)&rlds[wb + ldso[0]];

    // pointer bumps + q ownership fill the drain window
    qv[0] = qn0; qv[1] = qn1;
    const bool adv = (t <= T_STEPS - 3);
    np += adv ? (size_t)(BATCH * NH)  : (size_t)0;
    ip += adv ? (size_t)(BATCH * NIN) : (size_t)0;
    xp += (size_t)(BATCH * NH);

    // step rendezvous: drain LDS (NOT vmcnt — x-stores stay async), barrier
    asm volatile("s_waitcnt lgkmcnt(0)" ::: "memory");
    __builtin_amdgcn_s_barrier();
    asm volatile("" ::: "memory");  // no next-step LDS reads hoisted above
  }
}

// Phase 2: z_t = tanh(x_t) @ Wout + bout for all (t,b) — embarrassingly
// parallel over T*B/16 = 4096 independent 16-row x 16-out x 256-k tiles.
// Reads the f32 states written by phase 1 (same stream => ordered).
__global__ __launch_bounds__(256, 4)
void RecurrentNetwork_19628000543215_zkernel(
    const float* __restrict__ states,  // [T*B][NH]
    const float* __restrict__ Wout,    // [NH][NOUT]
    const float* __restrict__ bout,    // [NOUT]
    float* __restrict__ outz)          // [T*B][NOUT]
{
  const int tid  = threadIdx.x;
  const int wv   = tid >> 6;
  const int l    = tid & 63;
  const int m    = l & 15;
  const int q    = l >> 4;
  const int tile = blockIdx.x * 4 + wv;     // 0..4095
  const int row  = tile * 16 + m;           // flat (t*B + b)

  half8 wo[8];                      // Wout^T A-frags, same lane->k map
  #pragma unroll
  for (int kt = 0; kt < 8; ++kt)
    #pragma unroll
    for (int j = 0; j < 8; ++j)
      wo[kt][j] = (_Float16)Wout[(size_t)(32 * kt + 8 * q + j) * NOUT + m];

  f32x4 zac = *(const f32x4*)(bout + 4 * q);
  const float* xrow = states + (size_t)row * NH;

  #pragma unroll
  for (int kt = 0; kt < 8; ++kt) {
    const f32x4 xa = *(const f32x4*)(xrow + 32 * kt + 8 * q);
    const f32x4 xb = *(const f32x4*)(xrow + 32 * kt + 8 * q + 4);
    half8 rf;
    rf[0] = (_Float16)fast_tanh(xa.x);
    rf[1] = (_Float16)fast_tanh(xa.y);
    rf[2] = (_Float16)fast_tanh(xa.z);
    rf[3] = (_Float16)fast_tanh(xa.w);
    rf[4] = (_Float16)fast_tanh(xb.x);
    rf[5] = (_Float16)fast_tanh(xb.y);
    rf[6] = (_Float16)fast_tanh(xb.z);
    rf[7] = (_Float16)fast_tanh(xb.w);
    zac = __builtin_amdgcn_mfma_f32_16x16x32_f16(wo[kt], rf, zac, 0, 0, 0);
  }
  // C layout: col = lane&15 = row-in-tile, row = 4q+reg = nout
  *(f32x4*)(outz + (size_t)row * NOUT + 4 * q) = zac;
}

extern "C" void kernel_launch(void* const* d_in, const int* in_sizes, int n_in,
                              void* d_out, int out_size, void* d_ws, size_t ws_size,
                              hipStream_t stream) {
  (void)in_sizes; (void)n_in; (void)out_size; (void)d_ws; (void)ws_size;
  float* outz = (float*)d_out;
  float* outx = (float*)d_out + (size_t)T_STEPS * BATCH * NOUT;
  RecurrentNetwork_19628000543215_kernel<<<dim3(4), dim3(512), 0, stream>>>(
      (const float*)d_in[0],   // inputs
      (const float*)d_in[1],   // noise
      (const float*)d_in[2],   // x0
      (const float*)d_in[3],   // Win
      (const float*)d_in[4],   // Wrec
      (const float*)d_in[5],   // brec
      outx);
  RecurrentNetwork_19628000543215_zkernel<<<dim3(1024), dim3(256), 0, stream>>>(
      outx,
      (const float*)d_in[6],   // Wout
      (const float*)d_in[7],   // bout
      outz);
}

// Round 10
// 1095.326 us; speedup vs baseline: 1.3709x; 1.3709x over previous
//
#include <hip/hip_runtime.h>

#define T_STEPS 1024
#define BATCH   64
#define NIN     32
#define NH      256
#define NOUT    16

typedef __attribute__((ext_vector_type(8))) _Float16 half8;
typedef __attribute__((ext_vector_type(4))) _Float16 half4;
typedef __attribute__((ext_vector_type(4))) float    f32x4;

__device__ __forceinline__ float fast_tanh(float x) {
  // tanh(x) = 1 - 2/(exp2(2*log2e*x)+1); exp2->inf/0 gives correct +-1 tails
  float e = __builtin_amdgcn_exp2f(x * 2.8853900817779268f);
  return 1.0f - 2.0f * __builtin_amdgcn_rcpf(e + 1.0f);
}

// LDS layout (round-2, conflict-verified): rlds[buf][m][...] ushort, row
// stride 320 (40 blocks of 8); element n at blk=(n>>3)^(m&7), j=n&7.
#define ROW 320
#define BUFSZ (16 * 320)

// Round-13/14 (round-13 hit an infra failure, resubmitted unchanged):
// round-7 base (1112 us, best) + input-GEMM eviction.
//  Round-8's nt-split regressed (1429): in-order wave issue + no compiler
//  interleave => halved MFMA ILP and doubled exposed tail. Reverted.
//  New: phase-0 kernel precomputes U[t][b][n] = 0.1*(u@Win + brec) + q_t
//  (input-independent of the recurrence) across all CUs. Phase-1 loop:
//  K-loop 9->8 fragments (16 MFMAs), a-chain init = U (q/brec folded),
//  wave-1 u-staging path deleted (was the barrier straggler). U lives
//  IN-PLACE in the states buffer: U[t] row is consumed (use-waitcnt) by
//  the same wave strictly before its x[t] store to that row issues.
//  Kept (round-7 verified): own-frag bypass w/ rotated kt order, running
//  pointers, cvt_pkrtz, lgkmcnt(0)+s_barrier protocol, z in phase-2.

// ---- Phase 0: U = 0.1*(u@Win + brec) + q, over T*B/16 = 4096 tiles ----
__global__ __launch_bounds__(256, 2)
void RecurrentNetwork_19628000543215_ukernel(
    const float* __restrict__ inputs,  // [T*B][NIN]
    const float* __restrict__ noise,   // [T*B][NH]
    const float* __restrict__ Win,     // [NIN][NH]
    const float* __restrict__ brec,    // [NH]
    float* __restrict__ U)             // [T*B][NH] (= states buffer)
{
  const int tid = threadIdx.x;
  const int wv  = tid >> 6;
  const int l   = tid & 63;
  const int m   = l & 15;
  const int q   = l >> 4;

  // Win^T A-frags (0.1-scaled) + 0.1*brec, for all 16 n-tiles
  half8 wf[16];
  f32x4 bs[16];
  #pragma unroll
  for (int nt = 0; nt < 16; ++nt) {
    #pragma unroll
    for (int j = 0; j < 8; ++j)
      wf[nt][j] = (_Float16)(0.1f * Win[(size_t)(8 * q + j) * NH + 16 * nt + m]);
    bs[nt] = 0.1f * (*(const f32x4*)(brec + 16 * nt + 4 * q));
  }

  #pragma unroll
  for (int s = 0; s < 2; ++s) {
    const int tile = blockIdx.x * 4 + wv + s * 2048;   // 0..4095
    const int row  = tile * 16 + m;                    // flat t*B + b
    const float* up = inputs + (size_t)row * NIN + 8 * q;
    const f32x4 ua = *(const f32x4*)up;
    const f32x4 ub = *(const f32x4*)(up + 4);
    half8 uf;                        // B-frag: lane(m,q) = u[row][8q+j]
    uf[0]=(_Float16)ua.x; uf[1]=(_Float16)ua.y; uf[2]=(_Float16)ua.z; uf[3]=(_Float16)ua.w;
    uf[4]=(_Float16)ub.x; uf[5]=(_Float16)ub.y; uf[6]=(_Float16)ub.z; uf[7]=(_Float16)ub.w;

    const float* qp = noise + (size_t)row * NH;
    float*       Up = U     + (size_t)row * NH;
    #pragma unroll
    for (int nt = 0; nt < 16; ++nt) {
      f32x4 acc = bs[nt] + *(const f32x4*)(qp + 16 * nt + 4 * q);
      acc = __builtin_amdgcn_mfma_f32_16x16x32_f16(wf[nt], uf, acc, 0, 0, 0);
      // C layout: col = lane&15 = row-in-tile, row-of-C = 4q+reg = n
      *(f32x4*)(Up + 16 * nt + 4 * q) = acc;
    }
  }
}

// ---- Phase 1: recurrence (round-7 core, 8 fragments) ----
__global__ __launch_bounds__(512, 2)
void RecurrentNetwork_19628000543215_kernel(
    const float* __restrict__ Uu,      // [T][B][NH] precomputed (aliases outx)
    const float* __restrict__ x0,      // [B][NH]
    const float* __restrict__ Wrec,    // [NH][NH]
    float* __restrict__ outx)          // states [T][B][NH]
{
  __shared__ alignas(16) unsigned short rlds[2 * BUFSZ];

  const int g   = blockIdx.x;       // batch group: batches [16g, 16g+16)
  const int tid = threadIdx.x;
  const int w   = tid >> 6;         // wave 0..7: owns n-columns [32w, 32w+32)
  const int l   = tid & 63;
  const int m   = l & 15;           // batch-in-group (B col / C col)
  const int q   = l >> 4;           // quad
  const int b   = 16 * g + m;       // global batch
  const int mx  = m & 7;            // LDS swizzle key

  // ---- weights in ROTATED kt order: slot i holds kt=(w+i)&7; i=0 is the
  // wave's own fragment. A-frag (16x16x32): row=lane&15, k=32*kt+8*q+j.
  half8 wr[2][8];                   // 0.1*Wrec^T
  int   ldso[8];                    // LDS ushort-offset of fragment slot i
  #pragma unroll
  for (int i = 0; i < 8; ++i) {
    const int kt = (w + i) & 7;
    ldso[i] = m * ROW + ((((4 * kt + q) ^ mx)) << 3);
    #pragma unroll
    for (int nt = 0; nt < 2; ++nt) {
      const int n = 32 * w + 16 * nt + m;
      #pragma unroll
      for (int j = 0; j < 8; ++j) {
        const int k = 32 * kt + 8 * q + j;
        wr[nt][i][j] = (_Float16)(0.1f * Wrec[(size_t)k * NH + n]);
      }
    }
  }

  f32x4 x[2];
  #pragma unroll
  for (int nt = 0; nt < 2; ++nt)
    x[nt] = *(const f32x4*)(x0 + (size_t)b * NH + 32 * w + 16 * nt + 4 * q);

  // ---- preloop: r_{-1}=tanh(x0) -> buf0; U_0 -> regs ----
  #pragma unroll
  for (int nt = 0; nt < 2; ++nt) {
    const int n0 = 32 * w + 16 * nt + 4 * q;
    half4 r;
    r.x = (_Float16)fast_tanh(x[nt].x);
    r.y = (_Float16)fast_tanh(x[nt].y);
    r.z = (_Float16)fast_tanh(x[nt].z);
    r.w = (_Float16)fast_tanh(x[nt].w);
    const int blk = (n0 >> 3) ^ mx;
    *(half4*)&rlds[m * ROW + blk * 8 + (n0 & 7)] = r;
  }
  f32x4 qv[2];                      // qv = U_t (brec+q+u@Win folded)
  qv[0] = *(const f32x4*)(Uu + (size_t)b * NH + 32 * w + 4 * q);
  qv[1] = *(const f32x4*)(Uu + (size_t)b * NH + 32 * w + 16 + 4 * q);
  __syncthreads();

  half8 bfw = *(const half8*)&rlds[ldso[0]];   // own fragment, buf0

  // running prefetch/store pointers (avoid per-step 64-bit mul + clamp)
  const float* np = Uu   + (size_t)BATCH * NH + (size_t)b * NH + 32 * w + 4 * q;
  float*       xp = outx + (size_t)b * NH + 32 * w + 4 * q;

  // ---- time loop ----
  #pragma unroll 1
  for (int t = 0; t < T_STEPS; ++t) {
    const int rb = (t & 1) * BUFSZ;
    const int wb = BUFSZ - rb;

    // U_{t+1} prefetch (row min(t+1,1023) via gated pointer increment)
    const f32x4 qn0 = *(const f32x4*)np;
    const f32x4 qn1 = *(const f32x4*)(np + 16);

    // acc = U_t + r_{t-1}@(0.1*Wrec); a-chain init = U, b-chain init = 0;
    // slot parity split over rotated slots; slot 0 = own frag from regs.
    f32x4 accA[2], accB[2];
    accA[0] = qv[0]; accA[1] = qv[1];
    accB[0] = f32x4{0.f, 0.f, 0.f, 0.f};
    accB[1] = f32x4{0.f, 0.f, 0.f, 0.f};

    accA[0] = __builtin_amdgcn_mfma_f32_16x16x32_f16(wr[0][0], bfw, accA[0], 0, 0, 0);
    accA[1] = __builtin_amdgcn_mfma_f32_16x16x32_f16(wr[1][0], bfw, accA[1], 0, 0, 0);
    #pragma unroll
    for (int i = 1; i < 8; ++i) {
      const half8 bf = *(const half8*)&rlds[rb + ldso[i]];
      if (i & 1) {
        accB[0] = __builtin_amdgcn_mfma_f32_16x16x32_f16(wr[0][i], bf, accB[0], 0, 0, 0);
        accB[1] = __builtin_amdgcn_mfma_f32_16x16x32_f16(wr[1][i], bf, accB[1], 0, 0, 0);
      } else {
        accA[0] = __builtin_amdgcn_mfma_f32_16x16x32_f16(wr[0][i], bf, accA[0], 0, 0, 0);
        accA[1] = __builtin_amdgcn_mfma_f32_16x16x32_f16(wr[1][i], bf, accA[1], 0, 0, 0);
      }
    }

    // x_t = 0.9*x_{t-1} + (accA+accB)   [U folded into accA init]
    x[0] = 0.9f * x[0] + (accA[0] + accB[0]);
    x[1] = 0.9f * x[1] + (accA[1] + accB[1]);

    // r_t = tanh(x_t) -> fp16 (packed cvt) -> buf[(t+1)&1]
    #pragma unroll
    for (int nt = 0; nt < 2; ++nt) {
      const int n0 = 32 * w + 16 * nt + 4 * q;
      half4 r;
      auto plo = __builtin_amdgcn_cvt_pkrtz(fast_tanh(x[nt].x), fast_tanh(x[nt].y));
      auto phi = __builtin_amdgcn_cvt_pkrtz(fast_tanh(x[nt].z), fast_tanh(x[nt].w));
      r.x = plo.x; r.y = plo.y; r.z = phi.x; r.w = phi.y;
      const int blk = (n0 >> 3) ^ mx;
      *(half4*)&rlds[wb + m * ROW + blk * 8 + (n0 & 7)] = r;
    }

    // own-fragment self-read for step t+1 (wave-local bytes of wb; LDS is
    // in-order within a wave => sees our writes above; drained by the
    // lgkmcnt(0) below, so next step starts with bfw already in regs)
    asm volatile("" ::: "memory");  // keep this read below the writes
    bfw = *(const half8*)&rlds[wb + ldso[0]];

    // x-store + pointer bumps fill the lgkm drain window (vmcnt path).
    // Safe vs in-place U: U[t] was consumed (use-waitcnt) before this store.
    *(f32x4*)(xp)      = x[0];
    *(f32x4*)(xp + 16) = x[1];
    qv[0] = qn0; qv[1] = qn1;
    const bool adv = (t <= T_STEPS - 3);
    np += adv ? (size_t)(BATCH * NH) : (size_t)0;
    xp += (size_t)(BATCH * NH);

    // step rendezvous: drain LDS (NOT vmcnt — x-stores stay async), barrier
    asm volatile("s_waitcnt lgkmcnt(0)" ::: "memory");
    __builtin_amdgcn_s_barrier();
    asm volatile("" ::: "memory");  // no next-step LDS reads hoisted above
  }
}

// ---- Phase 2: z_t = tanh(x_t) @ Wout + bout, 4096 independent tiles ----
__global__ __launch_bounds__(256, 4)
void RecurrentNetwork_19628000543215_zkernel(
    const float* __restrict__ states,  // [T*B][NH]
    const float* __restrict__ Wout,    // [NH][NOUT]
    const float* __restrict__ bout,    // [NOUT]
    float* __restrict__ outz)          // [T*B][NOUT]
{
  const int tid  = threadIdx.x;
  const int wv   = tid >> 6;
  const int l    = tid & 63;
  const int m    = l & 15;
  const int q    = l >> 4;
  const int tile = blockIdx.x * 4 + wv;     // 0..4095
  const int row  = tile * 16 + m;           // flat (t*B + b)

  half8 wo[8];                      // Wout^T A-frags, same lane->k map
  #pragma unroll
  for (int kt = 0; kt < 8; ++kt)
    #pragma unroll
    for (int j = 0; j < 8; ++j)
      wo[kt][j] = (_Float16)Wout[(size_t)(32 * kt + 8 * q + j) * NOUT + m];

  f32x4 zac = *(const f32x4*)(bout + 4 * q);
  const float* xrow = states + (size_t)row * NH;

  #pragma unroll
  for (int kt = 0; kt < 8; ++kt) {
    const f32x4 xa = *(const f32x4*)(xrow + 32 * kt + 8 * q);
    const f32x4 xb = *(const f32x4*)(xrow + 32 * kt + 8 * q + 4);
    half8 rf;
    rf[0] = (_Float16)fast_tanh(xa.x);
    rf[1] = (_Float16)fast_tanh(xa.y);
    rf[2] = (_Float16)fast_tanh(xa.z);
    rf[3] = (_Float16)fast_tanh(xa.w);
    rf[4] = (_Float16)fast_tanh(xb.x);
    rf[5] = (_Float16)fast_tanh(xb.y);
    rf[6] = (_Float16)fast_tanh(xb.z);
    rf[7] = (_Float16)fast_tanh(xb.w);
    zac = __builtin_amdgcn_mfma_f32_16x16x32_f16(wo[kt], rf, zac, 0, 0, 0);
  }
  // C layout: col = lane&15 = row-in-tile, row = 4q+reg = nout
  *(f32x4*)(outz + (size_t)row * NOUT + 4 * q) = zac;
}

extern "C" void kernel_launch(void* const* d_in, const int* in_sizes, int n_in,
                              void* d_out, int out_size, void* d_ws, size_t ws_size,
                              hipStream_t stream) {
  (void)in_sizes; (void)n_in; (void)out_size; (void)d_ws; (void)ws_size;
  float* outz = (float*)d_out;
  float* outx = (float*)d_out + (size_t)T_STEPS * BATCH * NOUT;
  RecurrentNetwork_19628000543215_ukernel<<<dim3(512), dim3(256), 0, stream>>>(
      (const float*)d_in[0],   // inputs
      (const float*)d_in[1],   // noise
      (const float*)d_in[3],   // Win
      (const float*)d_in[5],   // brec
      outx);                   // U lives in-place in the states buffer
  RecurrentNetwork_19628000543215_kernel<<<dim3(4), dim3(512), 0, stream>>>(
      outx,                    // U (aliases outx; see in-place safety note)
      (const float*)d_in[2],   // x0
      (const float*)d_in[4],   // Wrec
      outx);
  RecurrentNetwork_19628000543215_zkernel<<<dim3(1024), dim3(256), 0, stream>>>(
      outx,
      (const float*)d_in[6],   // Wout
      (const float*)d_in[7],   // bout
      outz);
}

// Round 12
// 945.612 us; speedup vs baseline: 1.5880x; 1.1583x over previous
//
#include <hip/hip_runtime.h>

#define T_STEPS 1024
#define BATCH   64
#define NIN     32
#define NH      256
#define NOUT    16

typedef __attribute__((ext_vector_type(8))) _Float16 half8;
typedef __attribute__((ext_vector_type(4))) float    f32x4;

__device__ __forceinline__ float fast_tanh(float x) {
  // tanh(x) = 1 - 2/(exp2(2*log2e*x)+1); exp2->inf/0 gives correct +-1 tails
  float e = __builtin_amdgcn_exp2f(x * 2.8853900817779268f);
  return 1.0f - 2.0f * __builtin_amdgcn_rcpf(e + 1.0f);
}

// LDS layout (round-11): per m-row (640 B) 32 chunks of 16 B; chunk for
// (kt,q) at index (4*kt+q)^(m&7). Fragment k-map: k = 32*kt + (j<4 ? 4q+j
// : 16+4q+(j-4)) — chosen so the 8 r-values a lane computes ARE its own
// fragment (single ds_write_b128; own fragment kept in regs, no re-read).
// Bank pattern identical to the proven round-2 swizzle (2-way max).
#define ROWB 640
#define BUFB (16 * 640)

// Round-15/16 (r15 failed on cvt_pkrtz return-type mismatch; fixed w/ auto):
// round-13 base (946 us) + single-b128 r path + unroll x2.
//  1. k-map permutation (above): r round-trip 3 LDS ops -> 1. bfw = reg.
//  2. time loop unrolled x2: buffer offsets become compile-time 0/10240,
//     folded into ds-op immediates (kills per-step buffer address VALU).
//  Kept: 8x32 waves, own-frag-first MFMA order, 4 acc chains, U eviction
//  (phase 0), z eviction (phase 2), lgkmcnt(0)+s_barrier rendezvous,
//  x-stores/pointer bumps inside the drain window.

// ---- Phase 0: U = 0.1*(u@Win + brec) + q, over T*B/16 = 4096 tiles ----
__global__ __launch_bounds__(256, 2)
void RecurrentNetwork_19628000543215_ukernel(
    const float* __restrict__ inputs,  // [T*B][NIN]
    const float* __restrict__ noise,   // [T*B][NH]
    const float* __restrict__ Win,     // [NIN][NH]
    const float* __restrict__ brec,    // [NH]
    float* __restrict__ U)             // [T*B][NH] (= states buffer)
{
  const int tid = threadIdx.x;
  const int wv  = tid >> 6;
  const int l   = tid & 63;
  const int m   = l & 15;
  const int q   = l >> 4;

  // Win^T A-frags (0.1-scaled) + 0.1*brec, for all 16 n-tiles
  half8 wf[16];
  f32x4 bs[16];
  #pragma unroll
  for (int nt = 0; nt < 16; ++nt) {
    #pragma unroll
    for (int j = 0; j < 8; ++j)
      wf[nt][j] = (_Float16)(0.1f * Win[(size_t)(8 * q + j) * NH + 16 * nt + m]);
    bs[nt] = 0.1f * (*(const f32x4*)(brec + 16 * nt + 4 * q));
  }

  #pragma unroll
  for (int s = 0; s < 2; ++s) {
    const int tile = blockIdx.x * 4 + wv + s * 2048;   // 0..4095
    const int row  = tile * 16 + m;                    // flat t*B + b
    const float* up = inputs + (size_t)row * NIN + 8 * q;
    const f32x4 ua = *(const f32x4*)up;
    const f32x4 ub = *(const f32x4*)(up + 4);
    half8 uf;                        // B-frag: lane(m,q) = u[row][8q+j]
    uf[0]=(_Float16)ua.x; uf[1]=(_Float16)ua.y; uf[2]=(_Float16)ua.z; uf[3]=(_Float16)ua.w;
    uf[4]=(_Float16)ub.x; uf[5]=(_Float16)ub.y; uf[6]=(_Float16)ub.z; uf[7]=(_Float16)ub.w;

    const float* qp = noise + (size_t)row * NH;
    float*       Up = U     + (size_t)row * NH;
    #pragma unroll
    for (int nt = 0; nt < 16; ++nt) {
      f32x4 acc = bs[nt] + *(const f32x4*)(qp + 16 * nt + 4 * q);
      acc = __builtin_amdgcn_mfma_f32_16x16x32_f16(wf[nt], uf, acc, 0, 0, 0);
      // C layout: col = lane&15 = row-in-tile, row-of-C = 4q+reg = n
      *(f32x4*)(Up + 16 * nt + 4 * q) = acc;
    }
  }
}

// ---- Phase 1: recurrence ----
__global__ __launch_bounds__(512, 2)
void RecurrentNetwork_19628000543215_kernel(
    const float* __restrict__ Uu,      // [T][B][NH] precomputed (aliases outx)
    const float* __restrict__ x0,      // [B][NH]
    const float* __restrict__ Wrec,    // [NH][NH]
    float* __restrict__ outx)          // states [T][B][NH]
{
  __shared__ alignas(16) char rlds[2 * BUFB];

  const int g   = blockIdx.x;       // batch group: batches [16g, 16g+16)
  const int tid = threadIdx.x;
  const int w   = tid >> 6;         // wave 0..7: owns n-columns [32w, 32w+32)
  const int l   = tid & 63;
  const int m   = l & 15;           // batch-in-group (B col / C col)
  const int q   = l >> 4;           // quad
  const int b   = 16 * g + m;       // global batch
  const int mx  = m & 7;            // LDS swizzle key

  // ---- weights, rotated slot order (slot 0 = own kt=w), permuted k-map --
  half8 wr[2][8];                   // 0.1*Wrec^T; A-frag row = lane&15 = n
  int   ldso[8];                    // LDS byte offset of fragment slot i
  #pragma unroll
  for (int i = 0; i < 8; ++i) {
    const int kt = (w + i) & 7;
    ldso[i] = m * ROWB + (((4 * kt + q) ^ mx) << 4);
    #pragma unroll
    for (int nt = 0; nt < 2; ++nt) {
      const int n = 32 * w + 16 * nt + m;
      #pragma unroll
      for (int j = 0; j < 8; ++j) {
        const int kk = 32 * kt + (j < 4 ? 4 * q + j : 16 + 4 * q + (j - 4));
        wr[nt][i][j] = (_Float16)(0.1f * Wrec[(size_t)kk * NH + n]);
      }
    }
  }

  f32x4 x[2];                       // x[nt] = rows 4q..4q+3 of n-tile nt
  x[0] = *(const f32x4*)(x0 + (size_t)b * NH + 32 * w + 4 * q);
  x[1] = *(const f32x4*)(x0 + (size_t)b * NH + 32 * w + 16 + 4 * q);

  // ---- preloop: r_{-1}=tanh(x0) -> own b128 chunk of buf0; U_0 -> regs --
  half8 bfw;
  {
    const auto c0 = __builtin_amdgcn_cvt_pkrtz(fast_tanh(x[0].x), fast_tanh(x[0].y));
    const auto c1 = __builtin_amdgcn_cvt_pkrtz(fast_tanh(x[0].z), fast_tanh(x[0].w));
    const auto c2 = __builtin_amdgcn_cvt_pkrtz(fast_tanh(x[1].x), fast_tanh(x[1].y));
    const auto c3 = __builtin_amdgcn_cvt_pkrtz(fast_tanh(x[1].z), fast_tanh(x[1].w));
    half8 r;
    r[0]=(_Float16)c0.x; r[1]=(_Float16)c0.y; r[2]=(_Float16)c1.x; r[3]=(_Float16)c1.y;
    r[4]=(_Float16)c2.x; r[5]=(_Float16)c2.y; r[6]=(_Float16)c3.x; r[7]=(_Float16)c3.y;
    *(half8*)(rlds + ldso[0]) = r;  // buf0
    bfw = r;
  }
  f32x4 qv[2];                      // qv = U_t (brec+q+u@Win folded)
  qv[0] = *(const f32x4*)(Uu + (size_t)b * NH + 32 * w + 4 * q);
  qv[1] = *(const f32x4*)(Uu + (size_t)b * NH + 32 * w + 16 + 4 * q);
  __syncthreads();

  // running prefetch/store pointers
  const float* np = Uu   + (size_t)BATCH * NH + (size_t)b * NH + 32 * w + 4 * q;
  float*       xp = outx + (size_t)b * NH + 32 * w + 4 * q;

  // One step: read buf at byte offset RB, write own chunk at WB. RB/WB are
  // compile-time (0 / BUFB) => fold into ds-op immediates.
#define RNN_STEP(RB, WB, TCUR)                                               \
  {                                                                          \
    const f32x4 qn0 = *(const f32x4*)np;                                     \
    const f32x4 qn1 = *(const f32x4*)(np + 16);                              \
    const half8 bf1 = *(const half8*)(rlds + (RB) + ldso[1]);                \
    const half8 bf2 = *(const half8*)(rlds + (RB) + ldso[2]);                \
    const half8 bf3 = *(const half8*)(rlds + (RB) + ldso[3]);                \
    const half8 bf4 = *(const half8*)(rlds + (RB) + ldso[4]);                \
    const half8 bf5 = *(const half8*)(rlds + (RB) + ldso[5]);                \
    const half8 bf6 = *(const half8*)(rlds + (RB) + ldso[6]);                \
    const half8 bf7 = *(const half8*)(rlds + (RB) + ldso[7]);                \
    f32x4 accA0 = qv[0], accA1 = qv[1];                                      \
    f32x4 accB0 = f32x4{0.f,0.f,0.f,0.f}, accB1 = f32x4{0.f,0.f,0.f,0.f};    \
    accA0 = __builtin_amdgcn_mfma_f32_16x16x32_f16(wr[0][0], bfw, accA0, 0, 0, 0); \
    accA1 = __builtin_amdgcn_mfma_f32_16x16x32_f16(wr[1][0], bfw, accA1, 0, 0, 0); \
    accB0 = __builtin_amdgcn_mfma_f32_16x16x32_f16(wr[0][1], bf1, accB0, 0, 0, 0); \
    accB1 = __builtin_amdgcn_mfma_f32_16x16x32_f16(wr[1][1], bf1, accB1, 0, 0, 0); \
    accA0 = __builtin_amdgcn_mfma_f32_16x16x32_f16(wr[0][2], bf2, accA0, 0, 0, 0); \
    accA1 = __builtin_amdgcn_mfma_f32_16x16x32_f16(wr[1][2], bf2, accA1, 0, 0, 0); \
    accB0 = __builtin_amdgcn_mfma_f32_16x16x32_f16(wr[0][3], bf3, accB0, 0, 0, 0); \
    accB1 = __builtin_amdgcn_mfma_f32_16x16x32_f16(wr[1][3], bf3, accB1, 0, 0, 0); \
    accA0 = __builtin_amdgcn_mfma_f32_16x16x32_f16(wr[0][4], bf4, accA0, 0, 0, 0); \
    accA1 = __builtin_amdgcn_mfma_f32_16x16x32_f16(wr[1][4], bf4, accA1, 0, 0, 0); \
    accB0 = __builtin_amdgcn_mfma_f32_16x16x32_f16(wr[0][5], bf5, accB0, 0, 0, 0); \
    accB1 = __builtin_amdgcn_mfma_f32_16x16x32_f16(wr[1][5], bf5, accB1, 0, 0, 0); \
    accA0 = __builtin_amdgcn_mfma_f32_16x16x32_f16(wr[0][6], bf6, accA0, 0, 0, 0); \
    accA1 = __builtin_amdgcn_mfma_f32_16x16x32_f16(wr[1][6], bf6, accA1, 0, 0, 0); \
    accB0 = __builtin_amdgcn_mfma_f32_16x16x32_f16(wr[0][7], bf7, accB0, 0, 0, 0); \
    accB1 = __builtin_amdgcn_mfma_f32_16x16x32_f16(wr[1][7], bf7, accB1, 0, 0, 0); \
    x[0] = 0.9f * x[0] + (accA0 + accB0);                                    \
    x[1] = 0.9f * x[1] + (accA1 + accB1);                                    \
    {                                                                        \
      const auto c0 = __builtin_amdgcn_cvt_pkrtz(fast_tanh(x[0].x), fast_tanh(x[0].y)); \
      const auto c1 = __builtin_amdgcn_cvt_pkrtz(fast_tanh(x[0].z), fast_tanh(x[0].w)); \
      const auto c2 = __builtin_amdgcn_cvt_pkrtz(fast_tanh(x[1].x), fast_tanh(x[1].y)); \
      const auto c3 = __builtin_amdgcn_cvt_pkrtz(fast_tanh(x[1].z), fast_tanh(x[1].w)); \
      half8 r;                                                               \
      r[0]=(_Float16)c0.x; r[1]=(_Float16)c0.y;                              \
      r[2]=(_Float16)c1.x; r[3]=(_Float16)c1.y;                              \
      r[4]=(_Float16)c2.x; r[5]=(_Float16)c2.y;                              \
      r[6]=(_Float16)c3.x; r[7]=(_Float16)c3.y;                              \
      *(half8*)(rlds + (WB) + ldso[0]) = r;                                  \
      bfw = r;                                                               \
    }                                                                        \
    *(f32x4*)(xp)      = x[0];                                               \
    *(f32x4*)(xp + 16) = x[1];                                               \
    qv[0] = qn0; qv[1] = qn1;                                                \
    const bool adv = ((TCUR) <= T_STEPS - 3);                                \
    np += adv ? (size_t)(BATCH * NH) : (size_t)0;                            \
    xp += (size_t)(BATCH * NH);                                              \
    asm volatile("s_waitcnt lgkmcnt(0)" ::: "memory");                       \
    __builtin_amdgcn_s_barrier();                                            \
    asm volatile("" ::: "memory");                                           \
  }

  #pragma unroll 1
  for (int t = 0; t < T_STEPS; t += 2) {
    RNN_STEP(0,    BUFB, t)       // read buf0, write buf1
    RNN_STEP(BUFB, 0,    t + 1)   // read buf1, write buf0
  }
#undef RNN_STEP
}

// ---- Phase 2: z_t = tanh(x_t) @ Wout + bout, 4096 independent tiles ----
__global__ __launch_bounds__(256, 4)
void RecurrentNetwork_19628000543215_zkernel(
    const float* __restrict__ states,  // [T*B][NH]
    const float* __restrict__ Wout,    // [NH][NOUT]
    const float* __restrict__ bout,    // [NOUT]
    float* __restrict__ outz)          // [T*B][NOUT]
{
  const int tid  = threadIdx.x;
  const int wv   = tid >> 6;
  const int l    = tid & 63;
  const int m    = l & 15;
  const int q    = l >> 4;
  const int tile = blockIdx.x * 4 + wv;     // 0..4095
  const int row  = tile * 16 + m;           // flat (t*B + b)

  half8 wo[8];                      // Wout^T A-frags, same lane->k map
  #pragma unroll
  for (int kt = 0; kt < 8; ++kt)
    #pragma unroll
    for (int j = 0; j < 8; ++j)
      wo[kt][j] = (_Float16)Wout[(size_t)(32 * kt + 8 * q + j) * NOUT + m];

  f32x4 zac = *(const f32x4*)(bout + 4 * q);
  const float* xrow = states + (size_t)row * NH;

  #pragma unroll
  for (int kt = 0; kt < 8; ++kt) {
    const f32x4 xa = *(const f32x4*)(xrow + 32 * kt + 8 * q);
    const f32x4 xb = *(const f32x4*)(xrow + 32 * kt + 8 * q + 4);
    half8 rf;
    rf[0] = (_Float16)fast_tanh(xa.x);
    rf[1] = (_Float16)fast_tanh(xa.y);
    rf[2] = (_Float16)fast_tanh(xa.z);
    rf[3] = (_Float16)fast_tanh(xa.w);
    rf[4] = (_Float16)fast_tanh(xb.x);
    rf[5] = (_Float16)fast_tanh(xb.y);
    rf[6] = (_Float16)fast_tanh(xb.z);
    rf[7] = (_Float16)fast_tanh(xb.w);
    zac = __builtin_amdgcn_mfma_f32_16x16x32_f16(wo[kt], rf, zac, 0, 0, 0);
  }
  // C layout: col = lane&15 = row-in-tile, row = 4q+reg = nout
  *(f32x4*)(outz + (size_t)row * NOUT + 4 * q) = zac;
}

extern "C" void kernel_launch(void* const* d_in, const int* in_sizes, int n_in,
                              void* d_out, int out_size, void* d_ws, size_t ws_size,
                              hipStream_t stream) {
  (void)in_sizes; (void)n_in; (void)out_size; (void)d_ws; (void)ws_size;
  float* outz = (float*)d_out;
  float* outx = (float*)d_out + (size_t)T_STEPS * BATCH * NOUT;
  RecurrentNetwork_19628000543215_ukernel<<<dim3(512), dim3(256), 0, stream>>>(
      (const float*)d_in[0],   // inputs
      (const float*)d_in[1],   // noise
      (const float*)d_in[3],   // Win
      (const float*)d_in[5],   // brec
      outx);                   // U lives in-place in the states buffer
  RecurrentNetwork_19628000543215_kernel<<<dim3(4), dim3(512), 0, stream>>>(
      outx,                    // U (aliases outx; consumed before overwrite)
      (const float*)d_in[2],   // x0
      (const float*)d_in[4],   // Wrec
      outx);
  RecurrentNetwork_19628000543215_zkernel<<<dim3(1024), dim3(256), 0, stream>>>(
      outx,
      (const float*)d_in[6],   // Wout
      (const float*)d_in[7],   // bout
      outz);
}